// Round 1
// baseline (418.485 us; speedup 1.0000x reference)
//
#include <hip/hip_runtime.h>
#include <hip/hip_bf16.h>
#include <stdint.h>

#define NTOK 2048
#define HDIM 1024
#define NEXP 16
#define TOPK 4
#define IR   512
#define ISH  1024
#define RSCALE 2.5f

typedef short bf16x4 __attribute__((ext_vector_type(4)));
typedef short bf16x8 __attribute__((ext_vector_type(8)));
typedef float f32x4  __attribute__((ext_vector_type(4)));

static __device__ __forceinline__ unsigned short f2bf(float f){
  union { float fv; uint32_t u; } v; v.fv = f;
  uint32_t r = v.u + 0x7fffu + ((v.u >> 16) & 1u);
  return (unsigned short)(r >> 16);
}
static __device__ __forceinline__ float bf2f(unsigned short s){
  union { uint32_t u; float f; } v; v.u = ((uint32_t)s) << 16;
  return v.f;
}

// ---------------- router: logits, sigmoid, top-4, bucket append ----------------
__global__ __launch_bounds__(256) void router_kernel(
    const float* __restrict__ x, const float* __restrict__ gw,
    float* __restrict__ topkw, int* __restrict__ counts, int* __restrict__ lists)
{
  __shared__ float sgw[NEXP * (HDIM + 8)];
  const int tid = threadIdx.x;
  for (int f = tid; f < HDIM * NEXP; f += 256){
    int i = f >> 4, e = f & 15;
    sgw[e * (HDIM + 8) + i] = gw[f];
  }
  __syncthreads();
  const int lane = tid & 63;
  const int t = blockIdx.x * 4 + (tid >> 6);

  float s[NEXP];
  #pragma unroll
  for (int e = 0; e < NEXP; e++) s[e] = 0.f;
  #pragma unroll
  for (int j = 0; j < 16; j++){
    float xv = x[(size_t)t * HDIM + lane + 64 * j];
    #pragma unroll
    for (int e = 0; e < NEXP; e++)
      s[e] += xv * sgw[e * (HDIM + 8) + lane + 64 * j];
  }
  #pragma unroll
  for (int e = 0; e < NEXP; e++){
    #pragma unroll
    for (int off = 32; off; off >>= 1)
      s[e] += __shfl_xor(s[e], off);
  }
  float sc[NEXP];
  #pragma unroll
  for (int e = 0; e < NEXP; e++) sc[e] = 1.f / (1.f + __expf(-s[e]));

  unsigned mask = 0; float w[TOPK]; int id[TOPK];
  #pragma unroll
  for (int k = 0; k < TOPK; k++){
    float best = -1e30f; int bi = 0;
    #pragma unroll
    for (int e = 0; e < NEXP; e++){
      if (!((mask >> e) & 1u) && sc[e] > best){ best = sc[e]; bi = e; }
    }
    mask |= 1u << bi; id[k] = bi; w[k] = best;
  }
  float inv = 1.f / (w[0] + w[1] + w[2] + w[3]);
  if (lane == 0){
    #pragma unroll
    for (int k = 0; k < TOPK; k++){
      topkw[t * TOPK + k] = w[k] * inv;
      int pos = atomicAdd(&counts[id[k]], 1);
      lists[id[k] * NTOK + pos] = t * TOPK + k;
    }
  }
}

// ---------------- fused gate_up + SiLU*mul GEMM ----------------
// A: gathered token rows [count x HDIM] fp32 -> bf16
// B: [HDIM x 2*UPOFF] fp32 -> bf16, gate cols [n0,n0+64), up cols [UPOFF+n0, ...)
// out: act (bf16), row = aid (routed) or token (shared), ld = ACTLD
template<bool SH>
__global__ __launch_bounds__(256) void gu_kernel(
    const float* __restrict__ x, const float* __restrict__ wB,
    unsigned short* __restrict__ act,
    const int* __restrict__ lists, const int* __restrict__ counts)
{
  constexpr int LDB   = SH ? (2 * ISH) : (2 * IR);
  constexpr int UPOFF = SH ? ISH : IR;
  constexpr int ACTLD = SH ? ISH : IR;
  constexpr int BKP = 40;

  __shared__ unsigned short sA[64 * 32];
  __shared__ unsigned short sB[128 * BKP];
  __shared__ int sAid[64];

  const int e  = SH ? 0 : blockIdx.z;
  const int m0 = blockIdx.x * 64;
  const int n0 = blockIdx.y * 64;
  const int count = SH ? NTOK : counts[e];
  if (m0 >= count) return;
  const float* B = SH ? wB : (wB + (size_t)e * HDIM * (2 * IR));

  const int tid = threadIdx.x;
  if (tid < 64){
    int v;
    if (SH) v = m0 + tid;
    else    v = (m0 + tid < count) ? lists[e * NTOK + m0 + tid] : 0;
    sAid[tid] = v;
  }
  __syncthreads();

  const int wv = tid >> 6, lane = tid & 63;
  const int wm = wv >> 1, wn = wv & 1;
  const int lr = lane & 15, g = lane >> 4;

  const f32x4 zero4 = {0.f, 0.f, 0.f, 0.f};
  f32x4 accg[2][2], accu[2][2];
  #pragma unroll
  for (int i = 0; i < 2; i++)
    #pragma unroll
    for (int j = 0; j < 2; j++){ accg[i][j] = zero4; accu[i][j] = zero4; }

  const int cst = (wv & 1) * 64 + lane;
  const int gcst = (cst < 64) ? (n0 + cst) : (UPOFF + n0 + cst - 64);
  const int kbst = (wv >> 1) * 16;

  for (int k0 = 0; k0 < HDIM; k0 += 32){
    if (k0) __syncthreads();
    // stage A (gather rows, fp32 -> bf16)
    #pragma unroll
    for (int it = 0; it < 2; it++){
      int idx = tid + 256 * it;
      int r = idx >> 3, kq = (idx & 7) * 4;
      int v = sAid[r];
      int tok = SH ? v : (v >> 2);
      const float4 xv = *(const float4*)(x + (size_t)tok * HDIM + k0 + kq);
      bf16x4 pk = { (short)f2bf(xv.x), (short)f2bf(xv.y),
                    (short)f2bf(xv.z), (short)f2bf(xv.w) };
      *(bf16x4*)(sA + r * 32 + kq) = pk;
    }
    // stage B transposed: Bt[col][k]
    #pragma unroll
    for (int p = 0; p < 4; p++){
      const int kl = kbst + p * 4;
      const float* bp = B + (size_t)(k0 + kl) * LDB + gcst;
      bf16x4 pk = { (short)f2bf(bp[0]),       (short)f2bf(bp[LDB]),
                    (short)f2bf(bp[2 * LDB]), (short)f2bf(bp[3 * LDB]) };
      *(bf16x4*)(sB + cst * BKP + kl) = pk;
    }
    __syncthreads();

    bf16x8 a0 = *(const bf16x8*)(sA + (wm * 32 + lr) * 32 + g * 8);
    bf16x8 a1 = *(const bf16x8*)(sA + (wm * 32 + 16 + lr) * 32 + g * 8);
    #pragma unroll
    for (int ni = 0; ni < 2; ni++){
      const int cg = wn * 32 + ni * 16 + lr;
      bf16x8 bg = *(const bf16x8*)(sB + cg * BKP + g * 8);
      bf16x8 bu = *(const bf16x8*)(sB + (64 + cg) * BKP + g * 8);
      accg[0][ni] = __builtin_amdgcn_mfma_f32_16x16x32_bf16(a0, bg, accg[0][ni], 0, 0, 0);
      accg[1][ni] = __builtin_amdgcn_mfma_f32_16x16x32_bf16(a1, bg, accg[1][ni], 0, 0, 0);
      accu[0][ni] = __builtin_amdgcn_mfma_f32_16x16x32_bf16(a0, bu, accu[0][ni], 0, 0, 0);
      accu[1][ni] = __builtin_amdgcn_mfma_f32_16x16x32_bf16(a1, bu, accu[1][ni], 0, 0, 0);
    }
  }
  // epilogue: act = silu(gate) * up, store bf16
  #pragma unroll
  for (int mi = 0; mi < 2; mi++){
    #pragma unroll
    for (int r = 0; r < 4; r++){
      int row = wm * 32 + mi * 16 + g * 4 + r;
      if (!SH && (m0 + row >= count)) continue;
      int v = sAid[row];
      size_t arow = (size_t)v * ACTLD;
      #pragma unroll
      for (int ni = 0; ni < 2; ni++){
        float gv = accg[mi][ni][r];
        float uv = accu[mi][ni][r];
        float a = gv * (1.f / (1.f + __expf(-gv))) * uv;
        act[arow + n0 + wn * 32 + ni * 16 + lr] = f2bf(a);
      }
    }
  }
}

// ---------------- down GEMM ----------------
// A: gathered act rows (bf16, ld = K), B: [K x HDIM] fp32 -> bf16
// SH: store fp32 directly to out;  !SH: store bf16 to downout[aid][HDIM]
template<bool SH>
__global__ __launch_bounds__(256) void down_kernel(
    const unsigned short* __restrict__ act, const float* __restrict__ wB,
    float* __restrict__ outf, unsigned short* __restrict__ downout,
    const int* __restrict__ lists, const int* __restrict__ counts)
{
  constexpr int K = SH ? ISH : IR;
  constexpr int BKP = 40;

  __shared__ unsigned short sA[64 * 32];
  __shared__ unsigned short sB[128 * BKP];
  __shared__ int sAid[64];

  const int e  = SH ? 0 : blockIdx.z;
  const int m0 = blockIdx.x * 64;
  const int n0 = blockIdx.y * 128;
  const int count = SH ? NTOK : counts[e];
  if (m0 >= count) return;
  const float* B = SH ? wB : (wB + (size_t)e * K * HDIM);

  const int tid = threadIdx.x;
  if (tid < 64){
    int v;
    if (SH) v = m0 + tid;
    else    v = (m0 + tid < count) ? lists[e * NTOK + m0 + tid] : 0;
    sAid[tid] = v;
  }
  __syncthreads();

  const int wv = tid >> 6, lane = tid & 63;
  const int wm = wv >> 1, wn = wv & 1;
  const int lr = lane & 15, g = lane >> 4;

  const f32x4 zero4 = {0.f, 0.f, 0.f, 0.f};
  f32x4 acc[2][4];
  #pragma unroll
  for (int i = 0; i < 2; i++)
    #pragma unroll
    for (int j = 0; j < 4; j++) acc[i][j] = zero4;

  const int cst = (wv & 1) * 64 + lane;
  const int gcst = n0 + cst;
  const int kbst = (wv >> 1) * 16;
  const int ra = tid >> 2, kqa = (tid & 3) * 8;

  for (int k0 = 0; k0 < K; k0 += 32){
    if (k0) __syncthreads();
    {
      int v = sAid[ra];
      bf16x8 av = *(const bf16x8*)(act + (size_t)v * K + k0 + kqa);
      *(bf16x8*)(sA + ra * 32 + kqa) = av;
    }
    #pragma unroll
    for (int p = 0; p < 4; p++){
      const int kl = kbst + p * 4;
      const float* bp = B + (size_t)(k0 + kl) * HDIM + gcst;
      bf16x4 pk = { (short)f2bf(bp[0]),        (short)f2bf(bp[HDIM]),
                    (short)f2bf(bp[2 * HDIM]), (short)f2bf(bp[3 * HDIM]) };
      *(bf16x4*)(sB + cst * BKP + kl) = pk;
    }
    __syncthreads();

    bf16x8 a0 = *(const bf16x8*)(sA + (wm * 32 + lr) * 32 + g * 8);
    bf16x8 a1 = *(const bf16x8*)(sA + (wm * 32 + 16 + lr) * 32 + g * 8);
    #pragma unroll
    for (int ni = 0; ni < 4; ni++){
      const int cg = wn * 64 + ni * 16 + lr;
      bf16x8 bv = *(const bf16x8*)(sB + cg * BKP + g * 8);
      acc[0][ni] = __builtin_amdgcn_mfma_f32_16x16x32_bf16(a0, bv, acc[0][ni], 0, 0, 0);
      acc[1][ni] = __builtin_amdgcn_mfma_f32_16x16x32_bf16(a1, bv, acc[1][ni], 0, 0, 0);
    }
  }
  #pragma unroll
  for (int mi = 0; mi < 2; mi++){
    #pragma unroll
    for (int r = 0; r < 4; r++){
      int row = wm * 32 + mi * 16 + g * 4 + r;
      if (!SH && (m0 + row >= count)) continue;
      int v = sAid[row];
      #pragma unroll
      for (int ni = 0; ni < 4; ni++){
        int col = n0 + wn * 64 + ni * 16 + lr;
        float val = acc[mi][ni][r];
        if (SH) outf[(size_t)v * HDIM + col] = val;
        else    downout[(size_t)v * HDIM + col] = f2bf(val);
      }
    }
  }
}

// ---------------- combine: out = shared + RSCALE * sum_k w_k * down_k ----------------
__global__ __launch_bounds__(256) void combine_kernel(
    float* __restrict__ out, const unsigned short* __restrict__ downout,
    const float* __restrict__ topkw)
{
  const int idx = blockIdx.x * 256 + threadIdx.x;   // one float4 of out
  const int t = idx >> 8;                           // HDIM/4 = 256 per token
  const int c4 = (idx & 255) * 4;
  float4 o = *(float4*)(out + (size_t)t * HDIM + c4);
  float r0 = 0.f, r1 = 0.f, r2 = 0.f, r3 = 0.f;
  #pragma unroll
  for (int k = 0; k < TOPK; k++){
    float w = topkw[t * TOPK + k];
    const ushort4 dv = *(const ushort4*)(downout + (size_t)(t * TOPK + k) * HDIM + c4);
    r0 += w * bf2f(dv.x); r1 += w * bf2f(dv.y);
    r2 += w * bf2f(dv.z); r3 += w * bf2f(dv.w);
  }
  o.x += RSCALE * r0; o.y += RSCALE * r1; o.z += RSCALE * r2; o.w += RSCALE * r3;
  *(float4*)(out + (size_t)t * HDIM + c4) = o;
}

extern "C" void kernel_launch(void* const* d_in, const int* in_sizes, int n_in,
                              void* d_out, int out_size, void* d_ws, size_t ws_size,
                              hipStream_t stream) {
  const float* x   = (const float*)d_in[0];
  const float* gw  = (const float*)d_in[1];
  const float* wgu = (const float*)d_in[2];
  const float* wdn = (const float*)d_in[3];
  const float* sgu = (const float*)d_in[4];
  const float* sdn = (const float*)d_in[5];
  float* out = (float*)d_out;

  char* ws = (char*)d_ws;
  float* topkw = (float*)ws;                                   // 32 KB
  int* counts  = (int*)(ws + 32 * 1024);                       // 64 B (pad 256)
  int* lists   = (int*)(ws + 32 * 1024 + 256);                 // 128 KB
  size_t off = 32 * 1024 + 256 + 128 * 1024;                   // 164096, 16B aligned
  unsigned short* act_r   = (unsigned short*)(ws + off);                        // 8 MB
  unsigned short* act_s   = (unsigned short*)(ws + off + 8ull * 1024 * 1024);   // 4 MB
  unsigned short* downout = (unsigned short*)(ws + off + 12ull * 1024 * 1024);  // 16 MB

  hipMemsetAsync(counts, 0, 64, stream);
  router_kernel<<<NTOK / 4, 256, 0, stream>>>(x, gw, topkw, counts, lists);
  gu_kernel<false><<<dim3(NTOK / 64, IR / 64, NEXP), 256, 0, stream>>>(x, wgu, act_r, lists, counts);
  gu_kernel<true ><<<dim3(NTOK / 64, ISH / 64, 1),   256, 0, stream>>>(x, sgu, act_s, nullptr, nullptr);
  down_kernel<true ><<<dim3(NTOK / 64, HDIM / 128, 1),    256, 0, stream>>>(act_s, sdn, out, nullptr, nullptr, nullptr);
  down_kernel<false><<<dim3(NTOK / 64, HDIM / 128, NEXP), 256, 0, stream>>>(act_r, wdn, nullptr, downout, lists, counts);
  combine_kernel<<<(NTOK * HDIM / 4) / 256, 256, 0, stream>>>(out, downout, topkw);
}

// Round 2
// 294.104 us; speedup vs baseline: 1.4229x; 1.4229x over previous
//
#include <hip/hip_runtime.h>
#include <hip/hip_bf16.h>
#include <stdint.h>

#define NTOK 2048
#define HDIM 1024
#define NEXP 16
#define TOPK 4
#define IR   512
#define ISH  1024
#define RSCALE 2.5f

typedef short bf16x4 __attribute__((ext_vector_type(4)));
typedef short bf16x8 __attribute__((ext_vector_type(8)));
typedef float f32x4  __attribute__((ext_vector_type(4)));

static __device__ __forceinline__ unsigned short f2bf(float f){
  union { float fv; uint32_t u; } v; v.fv = f;
  uint32_t r = v.u + 0x7fffu + ((v.u >> 16) & 1u);
  return (unsigned short)(r >> 16);
}

static __device__ __forceinline__ void gl_lds16(const void* gp, void* lp){
  __builtin_amdgcn_global_load_lds(
      (const __attribute__((address_space(1))) unsigned int*)gp,
      (__attribute__((address_space(3))) unsigned int*)lp, 16, 0, 0);
}

// ---------- transpose + fp32->bf16 convert: src[R][C] f32 -> dst[C][R] bf16 ----------
__global__ __launch_bounds__(256) void convT_kernel(
    const float* __restrict__ src, unsigned short* __restrict__ dst, int R, int C)
{
  __shared__ float t[64 * 68];
  const int tid = threadIdx.x;
  const size_t bs = (size_t)R * C;
  const float* s = src + blockIdx.z * bs;
  unsigned short* d = dst + blockIdx.z * bs;
  const int c0 = blockIdx.x * 64, r0 = blockIdx.y * 64;
  #pragma unroll
  for (int i = 0; i < 4; i++){
    int r = i * 16 + (tid >> 4);
    int c = (tid & 15) * 4;
    float4 v = *(const float4*)(s + (size_t)(r0 + r) * C + c0 + c);
    *(float4*)(t + r * 68 + c) = v;
  }
  __syncthreads();
  #pragma unroll
  for (int i = 0; i < 4; i++){
    int c = i * 16 + (tid >> 4);    // output row (global col)
    int r = (tid & 15) * 4;
    bf16x4 pk = { (short)f2bf(t[(r    ) * 68 + c]), (short)f2bf(t[(r + 1) * 68 + c]),
                  (short)f2bf(t[(r + 2) * 68 + c]), (short)f2bf(t[(r + 3) * 68 + c]) };
    *(bf16x4*)(d + (size_t)(c0 + c) * R + r0 + r) = pk;
  }
}

// ---------------- router: logits, sigmoid, top-4, bucket append, x->bf16 ----------------
__global__ __launch_bounds__(256) void router_kernel(
    const float* __restrict__ x, const float* __restrict__ gw,
    float* __restrict__ topkw, int* __restrict__ counts, int* __restrict__ lists,
    unsigned short* __restrict__ xbf)
{
  __shared__ float sgw[NEXP * (HDIM + 8)];
  const int tid = threadIdx.x;
  for (int f = tid; f < HDIM * NEXP; f += 256){
    int i = f >> 4, e = f & 15;
    sgw[e * (HDIM + 8) + i] = gw[f];
  }
  __syncthreads();
  const int lane = tid & 63;
  const int t = blockIdx.x * 4 + (tid >> 6);

  float s[NEXP];
  #pragma unroll
  for (int e = 0; e < NEXP; e++) s[e] = 0.f;
  #pragma unroll
  for (int j = 0; j < 16; j++){
    float xv = x[(size_t)t * HDIM + lane + 64 * j];
    xbf[(size_t)t * HDIM + lane + 64 * j] = f2bf(xv);
    #pragma unroll
    for (int e = 0; e < NEXP; e++)
      s[e] += xv * sgw[e * (HDIM + 8) + lane + 64 * j];
  }
  #pragma unroll
  for (int e = 0; e < NEXP; e++){
    #pragma unroll
    for (int off = 32; off; off >>= 1)
      s[e] += __shfl_xor(s[e], off);
  }
  float sc[NEXP];
  #pragma unroll
  for (int e = 0; e < NEXP; e++) sc[e] = 1.f / (1.f + __expf(-s[e]));

  unsigned mask = 0; float w[TOPK]; int id[TOPK];
  #pragma unroll
  for (int k = 0; k < TOPK; k++){
    float best = -1e30f; int bi = 0;
    #pragma unroll
    for (int e = 0; e < NEXP; e++){
      if (!((mask >> e) & 1u) && sc[e] > best){ best = sc[e]; bi = e; }
    }
    mask |= 1u << bi; id[k] = bi; w[k] = best;
  }
  float inv = 1.f / (w[0] + w[1] + w[2] + w[3]);
  if (lane == 0){
    #pragma unroll
    for (int k = 0; k < TOPK; k++){
      topkw[t * TOPK + k] = w[k] * inv;
      int pos = atomicAdd(&counts[id[k]], 1);
      lists[id[k] * NTOK + pos] = t * TOPK + k;
    }
  }
}

// ---------------- fused gate_up GEMM + SiLU*mul, m97 structure ----------------
// A: xbf gathered rows [count x 1024]; B: wt [2*NPAIR x 1024] bf16 N-major.
// Block: BM=128, BN=128 (64 gate + 64 up pairs interleaved per 32 cols), BK=32.
template<bool SH>
__global__ __launch_bounds__(256) void gu_gemm(
    const unsigned short* __restrict__ xbf, const unsigned short* __restrict__ wt,
    unsigned short* __restrict__ act,
    const int* __restrict__ lists, const int* __restrict__ counts)
{
  constexpr int NPAIR = SH ? ISH : IR;
  constexpr int K = HDIM;
  constexpr int NCHUNK = SH ? 16 : 4;

  __shared__ unsigned short sA[128 * 32];
  __shared__ unsigned short sB[128 * 32];
  __shared__ int sAid[128];

  const int tid = threadIdx.x;
  const int e  = SH ? 0 : blockIdx.z;
  const int n0 = blockIdx.y * 64;                 // pair-column base
  const int count = SH ? NTOK : counts[e];
  const unsigned short* Bt = wt + (SH ? (size_t)0 : (size_t)e * (2 * IR) * K);

  const int wv = tid >> 6, lane = tid & 63, lr = lane & 15, g = lane >> 4;
  const int wm = wv >> 1, wn = wv & 1;

  // B staging sources (thread-constant)
  const unsigned short* bsrc[2];
  #pragma unroll
  for (int it = 0; it < 2; it++){
    int q = tid + it * 256;
    int c = q >> 2, ko = (q & 3) * 8;
    int grp = c >> 5, within = c & 31;
    int grow = n0 + (grp >> 1) * 32 + within + ((grp & 1) ? NPAIR : 0);
    bsrc[it] = Bt + (size_t)grow * K + ko;
  }

  for (int mt = blockIdx.x; mt * 128 < count; mt += NCHUNK){
    const int m0 = mt * 128;
    __syncthreads();
    if (tid < 128){
      int aid;
      if (SH) aid = m0 + tid;
      else { int idx = m0 + tid; aid = (idx < count) ? lists[e * NTOK + idx] : lists[e * NTOK]; }
      sAid[tid] = aid;
    }
    __syncthreads();
    const unsigned short* asrc[2];
    #pragma unroll
    for (int it = 0; it < 2; it++){
      int q = tid + it * 256;
      int r = q >> 2, ko = (q & 3) * 8;
      int aid = sAid[r];
      int tok = SH ? aid : (aid >> 2);
      asrc[it] = xbf + (size_t)tok * HDIM + ko;
    }

    const f32x4 z4 = {0.f, 0.f, 0.f, 0.f};
    f32x4 acc[4][4];
    #pragma unroll
    for (int i = 0; i < 4; i++)
      #pragma unroll
      for (int j = 0; j < 4; j++) acc[i][j] = z4;

    for (int k0 = 0; k0 < K; k0 += 32){
      #pragma unroll
      for (int it = 0; it < 2; it++){
        gl_lds16(asrc[it] + k0, sA + (tid + it * 256) * 8);
        gl_lds16(bsrc[it] + k0, sB + (tid + it * 256) * 8);
      }
      __syncthreads();
      bf16x8 af[4], bfr[4];
      #pragma unroll
      for (int i = 0; i < 4; i++){
        af[i]  = *(const bf16x8*)(sA + (wm * 64 + i * 16 + lr) * 32 + g * 8);
        bfr[i] = *(const bf16x8*)(sB + (wn * 64 + i * 16 + lr) * 32 + g * 8);
      }
      #pragma unroll
      for (int mi = 0; mi < 4; mi++)
        #pragma unroll
        for (int ni = 0; ni < 4; ni++)
          acc[mi][ni] = __builtin_amdgcn_mfma_f32_16x16x32_bf16(af[mi], bfr[ni], acc[mi][ni], 0, 0, 0);
      __syncthreads();
    }

    #pragma unroll
    for (int mi = 0; mi < 4; mi++){
      #pragma unroll
      for (int r = 0; r < 4; r++){
        int row = wm * 64 + mi * 16 + g * 4 + r;
        if (!SH && m0 + row >= count) continue;
        int aid = sAid[row];
        size_t arow = (size_t)aid * NPAIR;
        #pragma unroll
        for (int ni = 0; ni < 2; ni++){
          float gv = acc[mi][ni][r];
          float uv = acc[mi][ni + 2][r];
          float a = gv / (1.f + __expf(-gv)) * uv;
          act[arow + n0 + wn * 32 + ni * 16 + lr] = f2bf(a);
        }
      }
    }
  }
}

// ---------------- down GEMM, m97 structure ----------------
// A: act rows [.. x K] bf16; B: wt [1024 x K] bf16 N-major.
// SH: plain fp32 store to out. !SH: atomicAdd(RSCALE * topkw * val).
template<bool SH>
__global__ __launch_bounds__(256) void down_gemm(
    const unsigned short* __restrict__ act, const unsigned short* __restrict__ wt,
    float* __restrict__ out, const float* __restrict__ topkw,
    const int* __restrict__ lists, const int* __restrict__ counts)
{
  constexpr int K = SH ? ISH : IR;
  constexpr int NCHUNK = SH ? 16 : 4;

  __shared__ unsigned short sA[128 * 32];
  __shared__ unsigned short sB[128 * 32];
  __shared__ int sAid[128];

  const int tid = threadIdx.x;
  const int e  = SH ? 0 : blockIdx.z;
  const int n0 = blockIdx.y * 128;
  const int count = SH ? NTOK : counts[e];
  const unsigned short* Bt = wt + (SH ? (size_t)0 : (size_t)e * HDIM * K);

  const int wv = tid >> 6, lane = tid & 63, lr = lane & 15, g = lane >> 4;
  const int wm = wv >> 1, wn = wv & 1;

  const unsigned short* bsrc[2];
  #pragma unroll
  for (int it = 0; it < 2; it++){
    int q = tid + it * 256;
    int c = q >> 2, ko = (q & 3) * 8;
    bsrc[it] = Bt + (size_t)(n0 + c) * K + ko;
  }

  for (int mt = blockIdx.x; mt * 128 < count; mt += NCHUNK){
    const int m0 = mt * 128;
    __syncthreads();
    if (tid < 128){
      int aid;
      if (SH) aid = m0 + tid;
      else { int idx = m0 + tid; aid = (idx < count) ? lists[e * NTOK + idx] : lists[e * NTOK]; }
      sAid[tid] = aid;
    }
    __syncthreads();
    const unsigned short* asrc[2];
    #pragma unroll
    for (int it = 0; it < 2; it++){
      int q = tid + it * 256;
      int r = q >> 2, ko = (q & 3) * 8;
      asrc[it] = act + (size_t)sAid[r] * K + ko;
    }

    const f32x4 z4 = {0.f, 0.f, 0.f, 0.f};
    f32x4 acc[4][4];
    #pragma unroll
    for (int i = 0; i < 4; i++)
      #pragma unroll
      for (int j = 0; j < 4; j++) acc[i][j] = z4;

    for (int k0 = 0; k0 < K; k0 += 32){
      #pragma unroll
      for (int it = 0; it < 2; it++){
        gl_lds16(asrc[it] + k0, sA + (tid + it * 256) * 8);
        gl_lds16(bsrc[it] + k0, sB + (tid + it * 256) * 8);
      }
      __syncthreads();
      bf16x8 af[4], bfr[4];
      #pragma unroll
      for (int i = 0; i < 4; i++){
        af[i]  = *(const bf16x8*)(sA + (wm * 64 + i * 16 + lr) * 32 + g * 8);
        bfr[i] = *(const bf16x8*)(sB + (wn * 64 + i * 16 + lr) * 32 + g * 8);
      }
      #pragma unroll
      for (int mi = 0; mi < 4; mi++)
        #pragma unroll
        for (int ni = 0; ni < 4; ni++)
          acc[mi][ni] = __builtin_amdgcn_mfma_f32_16x16x32_bf16(af[mi], bfr[ni], acc[mi][ni], 0, 0, 0);
      __syncthreads();
    }

    #pragma unroll
    for (int mi = 0; mi < 4; mi++){
      #pragma unroll
      for (int r = 0; r < 4; r++){
        int row = wm * 64 + mi * 16 + g * 4 + r;
        if (!SH && m0 + row >= count) continue;
        int aid = sAid[row];
        if (SH){
          size_t orow = (size_t)aid * HDIM;
          #pragma unroll
          for (int ni = 0; ni < 4; ni++)
            out[orow + n0 + wn * 64 + ni * 16 + lr] = acc[mi][ni][r];
        } else {
          int tok = aid >> 2;
          float w = RSCALE * topkw[aid];
          size_t orow = (size_t)tok * HDIM;
          #pragma unroll
          for (int ni = 0; ni < 4; ni++)
            atomicAdd(&out[orow + n0 + wn * 64 + ni * 16 + lr], w * acc[mi][ni][r]);
        }
      }
    }
  }
}

extern "C" void kernel_launch(void* const* d_in, const int* in_sizes, int n_in,
                              void* d_out, int out_size, void* d_ws, size_t ws_size,
                              hipStream_t stream) {
  const float* x   = (const float*)d_in[0];
  const float* gw  = (const float*)d_in[1];
  const float* wgu = (const float*)d_in[2];
  const float* wdn = (const float*)d_in[3];
  const float* sgu = (const float*)d_in[4];
  const float* sdn = (const float*)d_in[5];
  float* out = (float*)d_out;

  char* ws = (char*)d_ws;
  float* topkw = (float*)(ws + 0);                       // 32768
  int* counts  = (int*)(ws + 32768);                     // 256
  int* lists   = (int*)(ws + 33024);                     // 131072 -> 164096
  unsigned short* xbf   = (unsigned short*)(ws + 164096);                  // 4 MB
  unsigned short* wgu_t = (unsigned short*)(ws + 164096 + 4194304ull);     // 32 MB
  unsigned short* wdn_t = (unsigned short*)(ws + 164096 + 37748736ull);    // 16 MB
  unsigned short* sgu_t = (unsigned short*)(ws + 164096 + 54525952ull);    // 4 MB
  unsigned short* sdn_t = (unsigned short*)(ws + 164096 + 58720256ull);    // 2 MB
  unsigned short* act_r = (unsigned short*)(ws + 164096 + 60817408ull);    // 8 MB
  unsigned short* act_s = (unsigned short*)(ws + 164096 + 69206016ull);    // 4 MB

  hipMemsetAsync(counts, 0, 64, stream);
  router_kernel<<<NTOK / 4, 256, 0, stream>>>(x, gw, topkw, counts, lists, xbf);
  // weight transpose+convert: src [R][C] f32 -> dst [C][R] bf16
  convT_kernel<<<dim3(16, 16, NEXP), 256, 0, stream>>>(wgu, wgu_t, HDIM, 2 * IR);
  convT_kernel<<<dim3(16,  8, NEXP), 256, 0, stream>>>(wdn, wdn_t, IR, HDIM);
  convT_kernel<<<dim3(32, 16, 1),    256, 0, stream>>>(sgu, sgu_t, HDIM, 2 * ISH);
  convT_kernel<<<dim3(16, 16, 1),    256, 0, stream>>>(sdn, sdn_t, ISH, HDIM);

  gu_gemm<true ><<<dim3(16, ISH / 64, 1),   256, 0, stream>>>(xbf, sgu_t, act_s, nullptr, nullptr);
  gu_gemm<false><<<dim3(4,  IR  / 64, NEXP), 256, 0, stream>>>(xbf, wgu_t, act_r, lists, counts);
  down_gemm<true ><<<dim3(16, HDIM / 128, 1),    256, 0, stream>>>(act_s, sdn_t, out, nullptr, nullptr, nullptr);
  down_gemm<false><<<dim3(4,  HDIM / 128, NEXP), 256, 0, stream>>>(act_r, wdn_t, out, topkw, lists, counts);
}

// Round 3
// 201.224 us; speedup vs baseline: 2.0797x; 1.4616x over previous
//
#include <hip/hip_runtime.h>
#include <hip/hip_bf16.h>
#include <stdint.h>

#define NTOK 2048
#define HDIM 1024
#define NEXP 16
#define TOPK 4
#define IR   512
#define ISH  1024
#define RSCALE 2.5f

typedef short bf16x4 __attribute__((ext_vector_type(4)));
typedef short bf16x8 __attribute__((ext_vector_type(8)));
typedef float f32x4  __attribute__((ext_vector_type(4)));

static __device__ __forceinline__ unsigned short f2bf(float f){
  union { float fv; uint32_t u; } v; v.fv = f;
  uint32_t r = v.u + 0x7fffu + ((v.u >> 16) & 1u);
  return (unsigned short)(r >> 16);
}

static __device__ __forceinline__ void gl_lds16(const void* gp, void* lp){
  __builtin_amdgcn_global_load_lds(
      (const __attribute__((address_space(1))) unsigned int*)gp,
      (__attribute__((address_space(3))) unsigned int*)lp, 16, 0, 0);
}

// ---------- transpose + fp32->bf16 convert: src[R][C] f32 -> dst[C][R] bf16 ----------
__global__ __launch_bounds__(256) void convT_kernel(
    const float* __restrict__ src, unsigned short* __restrict__ dst, int R, int C)
{
  __shared__ float t[64 * 68];
  const int tid = threadIdx.x;
  const size_t bs = (size_t)R * C;
  const float* s = src + blockIdx.z * bs;
  unsigned short* d = dst + blockIdx.z * bs;
  const int c0 = blockIdx.x * 64, r0 = blockIdx.y * 64;
  #pragma unroll
  for (int i = 0; i < 4; i++){
    int r = i * 16 + (tid >> 4);
    int c = (tid & 15) * 4;
    float4 v = *(const float4*)(s + (size_t)(r0 + r) * C + c0 + c);
    *(float4*)(t + r * 68 + c) = v;
  }
  __syncthreads();
  #pragma unroll
  for (int i = 0; i < 4; i++){
    int c = i * 16 + (tid >> 4);    // output row (global col)
    int r = (tid & 15) * 4;
    bf16x4 pk = { (short)f2bf(t[(r    ) * 68 + c]), (short)f2bf(t[(r + 1) * 68 + c]),
                  (short)f2bf(t[(r + 2) * 68 + c]), (short)f2bf(t[(r + 3) * 68 + c]) };
    *(bf16x4*)(d + (size_t)(c0 + c) * R + r0 + r) = pk;
  }
}

// ---------------- router: logits, sigmoid, top-4, choice list, x->bf16 (NO atomics) ----------------
__global__ __launch_bounds__(256) void router_kernel(
    const float* __restrict__ x, const float* __restrict__ gw,
    float* __restrict__ topkw, int* __restrict__ choice,
    unsigned short* __restrict__ xbf)
{
  __shared__ float sgw[NEXP][HDIM + 8];
  const int tid = threadIdx.x;
  for (int f = tid; f < HDIM * NEXP; f += 256){
    int i = f >> 4, e = f & 15;
    sgw[e][i] = gw[f];
  }
  __syncthreads();
  const int lane = tid & 63;
  const int t = blockIdx.x * 4 + (tid >> 6);

  float s[NEXP];
  #pragma unroll
  for (int e = 0; e < NEXP; e++) s[e] = 0.f;
  #pragma unroll
  for (int j = 0; j < 8; j++){
    const int off = 128 * j + lane * 2;
    float2 xv = *(const float2*)(x + (size_t)t * HDIM + off);
    ushort2 xs = { f2bf(xv.x), f2bf(xv.y) };
    *(ushort2*)(xbf + (size_t)t * HDIM + off) = xs;
    #pragma unroll
    for (int e = 0; e < NEXP; e++){
      float2 gv = *(const float2*)(&sgw[e][off]);
      s[e] += xv.x * gv.x + xv.y * gv.y;
    }
  }
  #pragma unroll
  for (int e = 0; e < NEXP; e++){
    #pragma unroll
    for (int off = 32; off; off >>= 1)
      s[e] += __shfl_xor(s[e], off);
  }
  float sc[NEXP];
  #pragma unroll
  for (int e = 0; e < NEXP; e++) sc[e] = 1.f / (1.f + __expf(-s[e]));

  unsigned mask = 0; float w[TOPK]; int id[TOPK];
  #pragma unroll
  for (int k = 0; k < TOPK; k++){
    float best = -1e30f; int bi = 0;
    #pragma unroll
    for (int e = 0; e < NEXP; e++){
      if (!((mask >> e) & 1u) && sc[e] > best){ best = sc[e]; bi = e; }
    }
    mask |= 1u << bi; id[k] = bi; w[k] = best;
  }
  float inv = 1.f / (w[0] + w[1] + w[2] + w[3]);
  if (lane == 0){
    #pragma unroll
    for (int k = 0; k < TOPK; k++){
      topkw[t * TOPK + k] = w[k] * inv;
      choice[t * TOPK + k] = id[k];
    }
  }
}

// ---------------- build per-expert lists deterministically (prefix scan, no atomics) ----------------
__global__ __launch_bounds__(256) void build_lists(
    const int* __restrict__ choice, int* __restrict__ counts, int* __restrict__ lists)
{
  const int e = blockIdx.x;
  const int tid = threadIdx.x;
  __shared__ int scnt[256];
  const int base = tid * 32;              // 256*32 = 8192 = NTOK*TOPK
  unsigned m = 0; int local = 0;
  #pragma unroll
  for (int i = 0; i < 32; i++){
    bool hit = (choice[base + i] == e);
    m |= (unsigned)hit << i;
    local += hit;
  }
  scnt[tid] = local;
  __syncthreads();
  int v = local;
  for (int off = 1; off < 256; off <<= 1){
    int add = (tid >= off) ? scnt[tid - off] : 0;
    __syncthreads();
    v += add; scnt[tid] = v;
    __syncthreads();
  }
  int pos = v - local;                    // exclusive prefix
  #pragma unroll
  for (int i = 0; i < 32; i++){
    if ((m >> i) & 1u) lists[e * NTOK + pos++] = base + i;
  }
  if (tid == 255) counts[e] = v;
}

// ---------------- fused gate_up GEMM + SiLU*mul, m97 structure ----------------
template<bool SH>
__global__ __launch_bounds__(256) void gu_gemm(
    const unsigned short* __restrict__ xbf, const unsigned short* __restrict__ wt,
    unsigned short* __restrict__ act,
    const int* __restrict__ lists, const int* __restrict__ counts)
{
  constexpr int NPAIR = SH ? ISH : IR;
  constexpr int K = HDIM;
  constexpr int NCHUNK = SH ? 16 : 4;

  __shared__ unsigned short sA[128 * 32];
  __shared__ unsigned short sB[128 * 32];
  __shared__ int sAid[128];

  const int tid = threadIdx.x;
  const int e  = SH ? 0 : blockIdx.z;
  const int n0 = blockIdx.y * 64;                 // pair-column base
  const int count = SH ? NTOK : counts[e];
  const unsigned short* Bt = wt + (SH ? (size_t)0 : (size_t)e * (2 * IR) * K);

  const int wv = tid >> 6, lane = tid & 63, lr = lane & 15, g = lane >> 4;
  const int wm = wv >> 1, wn = wv & 1;

  const unsigned short* bsrc[2];
  #pragma unroll
  for (int it = 0; it < 2; it++){
    int q = tid + it * 256;
    int c = q >> 2, ko = (q & 3) * 8;
    int grp = c >> 5, within = c & 31;
    int grow = n0 + (grp >> 1) * 32 + within + ((grp & 1) ? NPAIR : 0);
    bsrc[it] = Bt + (size_t)grow * K + ko;
  }

  for (int mt = blockIdx.x; mt * 128 < count; mt += NCHUNK){
    const int m0 = mt * 128;
    __syncthreads();
    if (tid < 128){
      int aid;
      if (SH) aid = m0 + tid;
      else { int idx = m0 + tid; aid = (idx < count) ? lists[e * NTOK + idx] : lists[e * NTOK]; }
      sAid[tid] = aid;
    }
    __syncthreads();
    const unsigned short* asrc[2];
    #pragma unroll
    for (int it = 0; it < 2; it++){
      int q = tid + it * 256;
      int r = q >> 2, ko = (q & 3) * 8;
      int aid = sAid[r];
      int tok = SH ? aid : (aid >> 2);
      asrc[it] = xbf + (size_t)tok * HDIM + ko;
    }

    const f32x4 z4 = {0.f, 0.f, 0.f, 0.f};
    f32x4 acc[4][4];
    #pragma unroll
    for (int i = 0; i < 4; i++)
      #pragma unroll
      for (int j = 0; j < 4; j++) acc[i][j] = z4;

    for (int k0 = 0; k0 < K; k0 += 32){
      #pragma unroll
      for (int it = 0; it < 2; it++){
        gl_lds16(asrc[it] + k0, sA + (tid + it * 256) * 8);
        gl_lds16(bsrc[it] + k0, sB + (tid + it * 256) * 8);
      }
      __syncthreads();
      bf16x8 af[4], bfr[4];
      #pragma unroll
      for (int i = 0; i < 4; i++){
        af[i]  = *(const bf16x8*)(sA + (wm * 64 + i * 16 + lr) * 32 + g * 8);
        bfr[i] = *(const bf16x8*)(sB + (wn * 64 + i * 16 + lr) * 32 + g * 8);
      }
      #pragma unroll
      for (int mi = 0; mi < 4; mi++)
        #pragma unroll
        for (int ni = 0; ni < 4; ni++)
          acc[mi][ni] = __builtin_amdgcn_mfma_f32_16x16x32_bf16(af[mi], bfr[ni], acc[mi][ni], 0, 0, 0);
      __syncthreads();
    }

    #pragma unroll
    for (int mi = 0; mi < 4; mi++){
      #pragma unroll
      for (int r = 0; r < 4; r++){
        int row = wm * 64 + mi * 16 + g * 4 + r;
        if (!SH && m0 + row >= count) continue;
        int aid = sAid[row];
        size_t arow = (size_t)aid * NPAIR;
        #pragma unroll
        for (int ni = 0; ni < 2; ni++){
          float gv = acc[mi][ni][r];
          float uv = acc[mi][ni + 2][r];
          float a = gv / (1.f + __expf(-gv)) * uv;
          act[arow + n0 + wn * 32 + ni * 16 + lr] = f2bf(a);
        }
      }
    }
  }
}

// ---------------- down GEMM, m97 structure ----------------
template<bool SH>
__global__ __launch_bounds__(256) void down_gemm(
    const unsigned short* __restrict__ act, const unsigned short* __restrict__ wt,
    float* __restrict__ out, const float* __restrict__ topkw,
    const int* __restrict__ lists, const int* __restrict__ counts)
{
  constexpr int K = SH ? ISH : IR;
  constexpr int NCHUNK = SH ? 16 : 4;

  __shared__ unsigned short sA[128 * 32];
  __shared__ unsigned short sB[128 * 32];
  __shared__ int sAid[128];

  const int tid = threadIdx.x;
  const int e  = SH ? 0 : blockIdx.z;
  const int n0 = blockIdx.y * 128;
  const int count = SH ? NTOK : counts[e];
  const unsigned short* Bt = wt + (SH ? (size_t)0 : (size_t)e * HDIM * K);

  const int wv = tid >> 6, lane = tid & 63, lr = lane & 15, g = lane >> 4;
  const int wm = wv >> 1, wn = wv & 1;

  const unsigned short* bsrc[2];
  #pragma unroll
  for (int it = 0; it < 2; it++){
    int q = tid + it * 256;
    int c = q >> 2, ko = (q & 3) * 8;
    bsrc[it] = Bt + (size_t)(n0 + c) * K + ko;
  }

  for (int mt = blockIdx.x; mt * 128 < count; mt += NCHUNK){
    const int m0 = mt * 128;
    __syncthreads();
    if (tid < 128){
      int aid;
      if (SH) aid = m0 + tid;
      else { int idx = m0 + tid; aid = (idx < count) ? lists[e * NTOK + idx] : lists[e * NTOK]; }
      sAid[tid] = aid;
    }
    __syncthreads();
    const unsigned short* asrc[2];
    #pragma unroll
    for (int it = 0; it < 2; it++){
      int q = tid + it * 256;
      int r = q >> 2, ko = (q & 3) * 8;
      asrc[it] = act + (size_t)sAid[r] * K + ko;
    }

    const f32x4 z4 = {0.f, 0.f, 0.f, 0.f};
    f32x4 acc[4][4];
    #pragma unroll
    for (int i = 0; i < 4; i++)
      #pragma unroll
      for (int j = 0; j < 4; j++) acc[i][j] = z4;

    for (int k0 = 0; k0 < K; k0 += 32){
      #pragma unroll
      for (int it = 0; it < 2; it++){
        gl_lds16(asrc[it] + k0, sA + (tid + it * 256) * 8);
        gl_lds16(bsrc[it] + k0, sB + (tid + it * 256) * 8);
      }
      __syncthreads();
      bf16x8 af[4], bfr[4];
      #pragma unroll
      for (int i = 0; i < 4; i++){
        af[i]  = *(const bf16x8*)(sA + (wm * 64 + i * 16 + lr) * 32 + g * 8);
        bfr[i] = *(const bf16x8*)(sB + (wn * 64 + i * 16 + lr) * 32 + g * 8);
      }
      #pragma unroll
      for (int mi = 0; mi < 4; mi++)
        #pragma unroll
        for (int ni = 0; ni < 4; ni++)
          acc[mi][ni] = __builtin_amdgcn_mfma_f32_16x16x32_bf16(af[mi], bfr[ni], acc[mi][ni], 0, 0, 0);
      __syncthreads();
    }

    #pragma unroll
    for (int mi = 0; mi < 4; mi++){
      #pragma unroll
      for (int r = 0; r < 4; r++){
        int row = wm * 64 + mi * 16 + g * 4 + r;
        if (!SH && m0 + row >= count) continue;
        int aid = sAid[row];
        if (SH){
          size_t orow = (size_t)aid * HDIM;
          #pragma unroll
          for (int ni = 0; ni < 4; ni++)
            out[orow + n0 + wn * 64 + ni * 16 + lr] = acc[mi][ni][r];
        } else {
          int tok = aid >> 2;
          float w = RSCALE * topkw[aid];
          size_t orow = (size_t)tok * HDIM;
          #pragma unroll
          for (int ni = 0; ni < 4; ni++)
            atomicAdd(&out[orow + n0 + wn * 64 + ni * 16 + lr], w * acc[mi][ni][r]);
        }
      }
    }
  }
}

extern "C" void kernel_launch(void* const* d_in, const int* in_sizes, int n_in,
                              void* d_out, int out_size, void* d_ws, size_t ws_size,
                              hipStream_t stream) {
  const float* x   = (const float*)d_in[0];
  const float* gw  = (const float*)d_in[1];
  const float* wgu = (const float*)d_in[2];
  const float* wdn = (const float*)d_in[3];
  const float* sgu = (const float*)d_in[4];
  const float* sdn = (const float*)d_in[5];
  float* out = (float*)d_out;

  char* ws = (char*)d_ws;
  float* topkw = (float*)(ws + 0);                        // 32 KB
  int* choice  = (int*)(ws + 32768);                      // 32 KB
  int* counts  = (int*)(ws + 65536);                      // 256 B
  int* lists   = (int*)(ws + 65792);                      // 128 KB -> ends 196864
  unsigned short* xbf   = (unsigned short*)(ws + 197120);                  // 4 MB
  unsigned short* wgu_t = (unsigned short*)(ws + 197120 + 4194304ull);     // 32 MB
  unsigned short* wdn_t = (unsigned short*)(ws + 197120 + 37748736ull);    // 16 MB
  unsigned short* sgu_t = (unsigned short*)(ws + 197120 + 54525952ull);    // 4 MB
  unsigned short* sdn_t = (unsigned short*)(ws + 197120 + 58720256ull);    // 2 MB
  unsigned short* act_r = (unsigned short*)(ws + 197120 + 60817408ull);    // 8 MB
  unsigned short* act_s = (unsigned short*)(ws + 197120 + 69206016ull);    // 4 MB

  router_kernel<<<NTOK / 4, 256, 0, stream>>>(x, gw, topkw, choice, xbf);
  build_lists<<<NEXP, 256, 0, stream>>>(choice, counts, lists);
  // weight transpose+convert: src [R][C] f32 -> dst [C][R] bf16
  convT_kernel<<<dim3(16, 16, NEXP), 256, 0, stream>>>(wgu, wgu_t, HDIM, 2 * IR);
  convT_kernel<<<dim3(16,  8, NEXP), 256, 0, stream>>>(wdn, wdn_t, IR, HDIM);
  convT_kernel<<<dim3(32, 16, 1),    256, 0, stream>>>(sgu, sgu_t, HDIM, 2 * ISH);
  convT_kernel<<<dim3(16, 16, 1),    256, 0, stream>>>(sdn, sdn_t, ISH, HDIM);

  gu_gemm<true ><<<dim3(16, ISH / 64, 1),    256, 0, stream>>>(xbf, sgu_t, act_s, nullptr, nullptr);
  gu_gemm<false><<<dim3(4,  IR  / 64, NEXP), 256, 0, stream>>>(xbf, wgu_t, act_r, lists, counts);
  down_gemm<true ><<<dim3(16, HDIM / 128, 1),    256, 0, stream>>>(act_s, sdn_t, out, nullptr, nullptr, nullptr);
  down_gemm<false><<<dim3(4,  HDIM / 128, NEXP), 256, 0, stream>>>(act_r, wdn_t, out, topkw, lists, counts);
}